// Round 18
// baseline (188.784 us; speedup 1.0000x reference)
//
#include <hip/hip_runtime.h>

#define DEV __device__ __forceinline__

typedef float f32x4 __attribute__((ext_vector_type(4)));
typedef float f32x16 __attribute__((ext_vector_type(16)));
typedef __bf16 bf16x8 __attribute__((ext_vector_type(8)));
typedef unsigned u32x4 __attribute__((ext_vector_type(4)));
typedef unsigned short u16x8 __attribute__((ext_vector_type(8)));

static constexpr int BB = 4, SS = 2048, DD = 1024, HH = 16;
static constexpr int MM = BB * SS;          // 8192 rows
static constexpr float LOG2_THETA_OVER_HALF = 0.4152410118609203f; // log2(10000)/32
static constexpr float SCL2 = 0.18033688011112042f;                // 0.125 * log2(e)

DEV unsigned short f2b(float f) {
    unsigned u = __float_as_uint(f);
    unsigned r = (u + 0x7fffu + ((u >> 16) & 1u)) >> 16;
    return (unsigned short)r;
}
DEV float b2f(unsigned short h) { return __uint_as_float(((unsigned)h) << 16); }

DEV void gload16(const void* g, void* l) {
    __builtin_amdgcn_global_load_lds((const __attribute__((address_space(1))) void*)g,
                                     (__attribute__((address_space(3))) void*)l, 16, 0, 0);
}

DEV unsigned cvtpk(float lo, float hi) {
    unsigned r;
    asm("v_cvt_pk_bf16_f32 %0, %1, %2" : "=v"(r) : "v"(lo), "v"(hi));
    return r;
}

#define PH_BAR do { __builtin_amdgcn_sched_barrier(0); __builtin_amdgcn_s_barrier(); __builtin_amdgcn_sched_barrier(0); } while (0)

// ---------------- fused prep: fp32->bf16 for x (blocks 0..8191) and weights (8192..12287) ----------------
__global__ __launch_bounds__(256) void k_prep(const float* __restrict__ x,
                                              const float* __restrict__ wq, const float* __restrict__ wk,
                                              const float* __restrict__ wv, const float* __restrict__ wo,
                                              unsigned short* __restrict__ xb,
                                              unsigned short* __restrict__ wqkvb) {
    int bid = blockIdx.x;
    if (bid < 8192) {
        int i = (bid * 256 + threadIdx.x) * 4;
        float4 v = *reinterpret_cast<const float4*>(x + i);
        ushort4 o;
        o.x = f2b(v.x); o.y = f2b(v.y); o.z = f2b(v.z); o.w = f2b(v.w);
        *reinterpret_cast<ushort4*>(xb + i) = o;
    } else {
        int b2 = bid - 8192;
        int t = b2 >> 10;
        const float* src = (t == 0) ? wq : (t == 1) ? wk : (t == 2) ? wv : wo;
        int i = ((b2 & 1023) * 256 + threadIdx.x) * 4;
        float4 v = *reinterpret_cast<const float4*>(src + i);
        ushort4 o;
        o.x = f2b(v.x); o.y = f2b(v.y); o.z = f2b(v.z); o.w = f2b(v.w);
        *reinterpret_cast<ushort4*>(wqkvb + (size_t)t * DD * DD + i) = o;
    }
}

// ---------------- 256x256 NT GEMM, BK=32, 64KB LDS -> 2 blocks/CU ----------------
// Round-12 phase pattern at BK=32: per tile 4 phases x 8 MFMA; stage B(T+2) ph2, A(T+2) ph3
// (1 gload16 call per [128][32] half). Ring 4 half-slots/operand, slot (2T+h)&3 holds 2 tiles.
// Boundary vmcnt(4) = tile T+1's 4 calls outstanding. Swizzle: phys chunk p of row R holds
// global chunk p^(R&3); read chunk = l4^(fr&3) (row&3 == fr&3 since rows are m*16+fr).
__global__ __launch_bounds__(512, 2) void k_gemm8(const unsigned short* __restrict__ A,
                                                  const unsigned short* __restrict__ Bw,
                                                  unsigned short* __restrict__ C, int ldc) {
    __shared__ __align__(16) unsigned short LdsA[4][128 * 32];
    __shared__ __align__(16) unsigned short LdsB[4][128 * 32];
    const int tid = threadIdx.x, lane = tid & 63, wid = tid >> 6;
    const int wm = wid >> 2, wn = wid & 3;
    const int fr = lane & 15, l4 = lane >> 4, sw2 = fr & 3;
    const int m0 = blockIdx.y * 256, n0 = blockIdx.x * 256;

    const int r0 = tid >> 2;                  // 0..127
    const int cg = (tid & 3) ^ (r0 & 3);      // pre-swizzled source chunk
    const unsigned short* aS = A  + (size_t)(m0 + r0) * 1024 + (cg << 3);
    const unsigned short* bS = Bw + (size_t)(n0 + r0) * 1024 + (cg << 3);
    unsigned short* dA = &LdsA[0][0];
    unsigned short* dB = &LdsB[0][0];
    const int dOf = wid * 512;                // wave-uniform: wave w covers bytes [w*1024, w*1024+1024)

    f32x4 acc[8][4] = {};

#define STGA(t, h) gload16(aS + (size_t)(t) * 32 + (size_t)(h) * 131072, dA + (((2 * (t) + (h)) & 3) * 4096) + dOf)
#define STGB(t, h) gload16(bS + (size_t)(t) * 32 + (size_t)(h) * 131072, dB + (((2 * (t) + (h)) & 3) * 4096) + dOf)

    // prologue: tile 0's 4 calls (oldest), then tile 1's 4
    STGB(0, 0); STGB(0, 1); STGA(0, 0); STGA(0, 1);
    STGB(1, 0); STGB(1, 1); STGA(1, 0); STGA(1, 1);

    bf16x8 aF[4], bL[2], bH[2];

    for (int T = 0; T < 32; ++T) {
        // boundary: tile T's 4 halves landed (newest 4 outstanding = tile T+1's)
        if (T < 31) { asm volatile("s_waitcnt vmcnt(4)" ::: "memory"); }
        else        { asm volatile("s_waitcnt vmcnt(0)" ::: "memory"); }
        PH_BAR;

        const unsigned short* As_ = &LdsA[(2 * T + wm) & 3][0];
        const unsigned short* Bs_ = &LdsB[(2 * T + (wn >> 1)) & 3][0];
        const int bro = (wn & 1) * 64;

        // ---- ph0: read aF m0-3 + bL n0-1; MFMA m0-3 x n0-1 ----
#pragma unroll
        for (int m = 0; m < 4; ++m)
            aF[m] = *(const bf16x8*)&As_[(m * 16 + fr) * 32 + ((l4 ^ sw2) << 3)];
#pragma unroll
        for (int n = 0; n < 2; ++n)
            bL[n] = *(const bf16x8*)&Bs_[(bro + n * 16 + fr) * 32 + ((l4 ^ sw2) << 3)];
        __builtin_amdgcn_s_setprio(1);
#pragma unroll
        for (int m = 0; m < 4; ++m)
#pragma unroll
            for (int n = 0; n < 2; ++n)
                acc[m][n] = __builtin_amdgcn_mfma_f32_16x16x32_bf16(aF[m], bL[n], acc[m][n], 0, 0, 0);
        __builtin_amdgcn_s_setprio(0);
        PH_BAR;

        // ---- ph1: read bH n2-3; MFMA m0-3 x n2-3 ----
#pragma unroll
        for (int n = 0; n < 2; ++n)
            bH[n] = *(const bf16x8*)&Bs_[(bro + (n + 2) * 16 + fr) * 32 + ((l4 ^ sw2) << 3)];
        __builtin_amdgcn_s_setprio(1);
#pragma unroll
        for (int m = 0; m < 4; ++m)
#pragma unroll
            for (int n = 0; n < 2; ++n)
                acc[m][n + 2] = __builtin_amdgcn_mfma_f32_16x16x32_bf16(aF[m], bH[n], acc[m][n + 2], 0, 0, 0);
        __builtin_amdgcn_s_setprio(0);
        PH_BAR;

        // ---- ph2: read aF m4-7; STG B(T+2) (B slots freed at ph1-end); MFMA m4-7 x n2-3 ----
#pragma unroll
        for (int m = 0; m < 4; ++m)
            aF[m] = *(const bf16x8*)&As_[((m + 4) * 16 + fr) * 32 + ((l4 ^ sw2) << 3)];
        if (T + 2 < 32) { STGB(T + 2, 0); STGB(T + 2, 1); }
        __builtin_amdgcn_s_setprio(1);
#pragma unroll
        for (int m = 0; m < 4; ++m)
#pragma unroll
            for (int n = 0; n < 2; ++n)
                acc[m + 4][n + 2] = __builtin_amdgcn_mfma_f32_16x16x32_bf16(aF[m], bH[n], acc[m + 4][n + 2], 0, 0, 0);
        __builtin_amdgcn_s_setprio(0);
        PH_BAR;

        // ---- ph3: STG A(T+2) (A slots freed at ph2-end); MFMA m4-7 x n0-1 ----
        if (T + 2 < 32) { STGA(T + 2, 0); STGA(T + 2, 1); }
        __builtin_amdgcn_s_setprio(1);
#pragma unroll
        for (int m = 0; m < 4; ++m)
#pragma unroll
            for (int n = 0; n < 2; ++n)
                acc[m + 4][n] = __builtin_amdgcn_mfma_f32_16x16x32_bf16(aF[m], bL[n], acc[m + 4][n], 0, 0, 0);
        __builtin_amdgcn_s_setprio(0);
        // ph3-end barrier provided by next boundary's PH_BAR
    }
#undef STGA
#undef STGB

    const int rb = l4 * 4;
#pragma unroll
    for (int m = 0; m < 8; ++m)
#pragma unroll
        for (int n = 0; n < 4; ++n)
#pragma unroll
            for (int r = 0; r < 4; ++r) {
                int row = m0 + wm * 128 + m * 16 + rb + r;
                int col = n0 + wn * 64 + n * 16 + fr;
                C[(size_t)row * ldc + col] = f2b(acc[m][n][r]);
            }
}

// ---------------- NT GEMM (m97 128x128): C[M,N] = A * Bw^T — proven O-proj ----------------
template <int OUTF32>
__global__ __launch_bounds__(256) void k_gemm(const unsigned short* __restrict__ A,
                                              const unsigned short* __restrict__ Bw,
                                              void* __restrict__ Cp, int ldc) {
    __shared__ __align__(16) unsigned short As[128 * 32];
    __shared__ __align__(16) unsigned short Bs[128 * 32];
    const int tid = threadIdx.x;
    const int lane = tid & 63, wid = tid >> 6;
    const int wm = wid >> 1, wn = wid & 1;
    const int fr = lane & 15, fk8 = (lane >> 4) * 8;
    const int m0 = blockIdx.y * 128, n0 = blockIdx.x * 128;
    const int r0 = tid >> 2, c0 = (tid & 3) * 8;

    f32x4 acc[4][4] = {};

    for (int kt = 0; kt < 1024; kt += 32) {
        gload16(&A[(size_t)(m0 + r0) * 1024 + kt + c0],       (unsigned short*)As + wid * 512);
        gload16(&A[(size_t)(m0 + 64 + r0) * 1024 + kt + c0],  (unsigned short*)As + 2048 + wid * 512);
        gload16(&Bw[(size_t)(n0 + r0) * 1024 + kt + c0],      (unsigned short*)Bs + wid * 512);
        gload16(&Bw[(size_t)(n0 + 64 + r0) * 1024 + kt + c0], (unsigned short*)Bs + 2048 + wid * 512);
        __syncthreads();

        bf16x8 af[4], bfv[4];
#pragma unroll
        for (int i = 0; i < 4; i++)
            af[i] = *(const bf16x8*)&As[(wm * 64 + i * 16 + fr) * 32 + fk8];
#pragma unroll
        for (int j = 0; j < 4; j++)
            bfv[j] = *(const bf16x8*)&Bs[(wn * 64 + j * 16 + fr) * 32 + fk8];
#pragma unroll
        for (int i = 0; i < 4; i++)
#pragma unroll
            for (int j = 0; j < 4; j++)
                acc[i][j] = __builtin_amdgcn_mfma_f32_16x16x32_bf16(af[i], bfv[j], acc[i][j], 0, 0, 0);
        __syncthreads();
    }

    const int rb = (lane >> 4) * 4;
#pragma unroll
    for (int i = 0; i < 4; i++)
#pragma unroll
        for (int j = 0; j < 4; j++)
#pragma unroll
            for (int r = 0; r < 4; r++) {
                int row = m0 + wm * 64 + i * 16 + rb + r;
                int col = n0 + wn * 64 + j * 16 + fr;
                if (OUTF32) ((float*)Cp)[(size_t)row * ldc + col] = acc[i][j][r];
                else        ((unsigned short*)Cp)[(size_t)row * ldc + col] = f2b(acc[i][j][r]);
            }
}

// ---------------- fused RoPE(Q,K) + V-transpose, co-dispatched ----------------
__global__ __launch_bounds__(256) void k_ropevt(unsigned short* __restrict__ QKV,
                                                unsigned short* __restrict__ Vt) {
    __shared__ unsigned short T[64 * 65];
    const int bid = blockIdx.x, tid = threadIdx.x;
    if (bid < 16384) {
        int g = bid * 256 + tid;              // pair index over M*512
        int m = g >> 9, p = g & 511;
        int i = p & 31;
        int s = m & (SS - 1);
        int col = ((p >> 5) << 6) + (i << 1); // h*64 + 2i
        float inv = exp2f(-(float)i * LOG2_THETA_OVER_HALF);
        float ang = (float)s * inv;
        float sn, cs;
        sincosf(ang, &sn, &cs);
        unsigned short* q2 = QKV + (size_t)m * 3072 + col;
        unsigned short* k2 = q2 + 1024;
        float q1 = b2f(q2[0]), q2v = b2f(q2[1]);
        float k1 = b2f(k2[0]), k2v = b2f(k2[1]);
        q2[0] = f2b((q1 * cs - q2v * sn) * SCL2);
        q2[1] = f2b((q1 * sn + q2v * cs) * SCL2);
        k2[0] = f2b(k1 * cs - k2v * sn);
        k2[1] = f2b(k1 * sn + k2v * cs);
    } else {
        const int v2 = bid - 16384;
        const int s0 = (v2 & 31) * 64, bh = v2 >> 5;
        const int b = bh >> 4, h = bh & 15;
        const int r = tid >> 3, c8 = (tid & 7) * 8;
        const unsigned short* V = QKV + 2 * DD;
#pragma unroll
        for (int p = 0; p < 2; p++) {
            int row = p * 32 + r;
            u16x8 v = *(const u16x8*)&V[(size_t)(b * SS + s0 + row) * 3072 + h * 64 + c8];
#pragma unroll
            for (int j = 0; j < 8; j++) T[(c8 + j) * 65 + row] = v[j];
        }
        __syncthreads();
#pragma unroll
        for (int p = 0; p < 2; p++) {
            int d = p * 32 + r;
            u16x8 o;
#pragma unroll
            for (int j = 0; j < 8; j++) o[j] = T[d * 65 + c8 + j];
            *(u16x8*)&Vt[((size_t)bh * 64 + d) * 2048 + s0 + c8] = o;
        }
    }
}

// pack exp'd scores into PV B-operand via permlane32_swap
DEV void packp(const f32x16& s, bf16x8* pf) {
#pragma unroll
    for (int g = 0; g < 2; g++) {
        unsigned w0 = cvtpk(s[8 * g + 0], s[8 * g + 1]);
        unsigned w1 = cvtpk(s[8 * g + 2], s[8 * g + 3]);
        unsigned w2 = cvtpk(s[8 * g + 4], s[8 * g + 5]);
        unsigned w3 = cvtpk(s[8 * g + 6], s[8 * g + 7]);
        asm("v_permlane32_swap_b32 %0, %1" : "+v"(w0), "+v"(w2));
        asm("v_permlane32_swap_b32 %0, %1" : "+v"(w1), "+v"(w3));
        u32x4 pd;
        pd[0] = w0; pd[1] = w1; pd[2] = w2; pd[3] = w3;
        pf[g] = __builtin_bit_cast(bf16x8, pd);
    }
}

DEV float sum16(const f32x16& s) {
    return (((s[0] + s[1]) + (s[2] + s[3])) + ((s[4] + s[5]) + (s[6] + s[7]))) +
           (((s[8] + s[9]) + (s[10] + s[11])) + (((s[12] + s[13]) + (s[14] + s[15]))));
}

// ---------------- causal flash attention: 8 waves x 32 q-rows, swapped 32x32 MFMA ----------------
// RING-3 K/V buffers + counted vmcnt (round-17, neutral-kept).
__global__ __launch_bounds__(512, 4) void k_attn(const unsigned short* __restrict__ QKV,
                                                 const unsigned short* __restrict__ Vt,
                                                 unsigned short* __restrict__ O) {
    __shared__ __align__(16) unsigned short Kbuf[3][64 * 64];
    __shared__ __align__(16) unsigned short Vbuf[3][64 * 64];
    const int tid = threadIdx.x, lane = tid & 63, wid = tid >> 6;
    const int l31 = lane & 31, hi = lane >> 5;
    const int bh = blockIdx.x, b = bh >> 4, h = bh & 15;
    const int qt = gridDim.y - 1 - blockIdx.y;       // long blocks first
    const int q0 = qt * 256;
    const int wq0 = q0 + wid * 32;
    const int tdw = wq0 >> 6;
    const int nk = (q0 + 256) >> 6;                  // >= 4 always

    const int srow = tid >> 3, sc = tid & 7;
    const unsigned short* ksrc = QKV + 1024 + ((size_t)(b * SS) + srow) * 3072 + h * 64 + ((sc ^ (srow & 7)) << 3);
    const unsigned short* vsrc = Vt + ((size_t)(bh * 64) + srow) * 2048 + ((sc ^ (srow & 7)) << 3);

    const unsigned short* qp = QKV + (size_t)(b * SS + wq0 + l31) * 3072 + h * 64;
    bf16x8 qf[4];
#pragma unroll
    for (int dt = 0; dt < 4; dt++) qf[dt] = *(const bf16x8*)(qp + dt * 16 + hi * 8);

    f32x16 oacc0 = {}, oacc1 = {};
    float lrow = 0.f;
    const int swz = l31 & 7;

    // prologue: stage tiles 0 and 1
    gload16(ksrc,             (unsigned short*)Kbuf[0] + wid * 512);
    gload16(vsrc,             (unsigned short*)Vbuf[0] + wid * 512);
    gload16(ksrc + 64 * 3072, (unsigned short*)Kbuf[1] + wid * 512);
    gload16(vsrc + 64,        (unsigned short*)Vbuf[1] + wid * 512);

    for (int t = 0; t < nk; t++) {
        if (t + 1 < nk) { asm volatile("s_waitcnt vmcnt(2) lgkmcnt(0)" ::: "memory"); }
        else            { asm volatile("s_waitcnt vmcnt(0) lgkmcnt(0)" ::: "memory"); }
        PH_BAR;
        if (t + 2 < nk) {
            int nb = (t + 2) % 3;
            gload16(ksrc + (size_t)(t + 2) * 64 * 3072, (unsigned short*)Kbuf[nb] + wid * 512);
            gload16(vsrc + (t + 2) * 64,                (unsigned short*)Vbuf[nb] + wid * 512);
        }
        if (t > tdw) continue;
        const unsigned short* Ks = Kbuf[t % 3];
        const unsigned short* Vs = Vbuf[t % 3];

        if (t < tdw) {
            // ---- full 64-k tile: two independent 32-k chains, straight-line (ILP) ----
            f32x16 s0 = {}, s1 = {};
            __builtin_amdgcn_s_setprio(1);
#pragma unroll
            for (int dt = 0; dt < 4; dt++) {
                bf16x8 kf = *(const bf16x8*)&Ks[l31 * 64 + (((dt * 2 + hi) ^ swz) << 3)];
                s0 = __builtin_amdgcn_mfma_f32_32x32x16_bf16(kf, qf[dt], s0, 0, 0, 0);
            }
#pragma unroll
            for (int dt = 0; dt < 4; dt++) {
                bf16x8 kf = *(const bf16x8*)&Ks[(32 + l31) * 64 + (((dt * 2 + hi) ^ swz) << 3)];
                s1 = __builtin_amdgcn_mfma_f32_32x32x16_bf16(kf, qf[dt], s1, 0, 0, 0);
            }
            __builtin_amdgcn_s_setprio(0);
#pragma unroll
            for (int r = 0; r < 16; r++) {
                s0[r] = __builtin_amdgcn_exp2f(s0[r]);
                s1[r] = __builtin_amdgcn_exp2f(s1[r]);
            }
            lrow += sum16(s0) + sum16(s1);
            bf16x8 pA[2], pB[2];
            packp(s0, pA);
            packp(s1, pB);
            __builtin_amdgcn_s_setprio(1);
#pragma unroll
            for (int g = 0; g < 2; g++) {
                bf16x8 vf0 = *(const bf16x8*)&Vs[l31 * 64 + (((g * 2 + hi) ^ swz) << 3)];
                oacc0 = __builtin_amdgcn_mfma_f32_32x32x16_bf16(vf0, pA[g], oacc0, 0, 0, 0);
                bf16x8 vf1 = *(const bf16x8*)&Vs[(32 + l31) * 64 + (((g * 2 + hi) ^ swz) << 3)];
                oacc1 = __builtin_amdgcn_mfma_f32_32x32x16_bf16(vf1, pA[g], oacc1, 0, 0, 0);
            }
#pragma unroll
            for (int g = 0; g < 2; g++) {
                bf16x8 vf0 = *(const bf16x8*)&Vs[l31 * 64 + (((4 + g * 2 + hi) ^ swz) << 3)];
                oacc0 = __builtin_amdgcn_mfma_f32_32x32x16_bf16(vf0, pB[g], oacc0, 0, 0, 0);
                bf16x8 vf1 = *(const bf16x8*)&Vs[(32 + l31) * 64 + (((4 + g * 2 + hi) ^ swz) << 3)];
                oacc1 = __builtin_amdgcn_mfma_f32_32x32x16_bf16(vf1, pB[g], oacc1, 0, 0, 0);
            }
            __builtin_amdgcn_s_setprio(0);
        } else {
            // ---- diagonal tile: masked path ----
#pragma unroll
            for (int kt2 = 0; kt2 < 2; kt2++) {
                const int kb = t * 64 + kt2 * 32;
                if (kb > wq0) break;

                f32x16 sacc = {};
                __builtin_amdgcn_s_setprio(1);
#pragma unroll
                for (int dt = 0; dt < 4; dt++) {
                    bf16x8 kf = *(const bf16x8*)&Ks[(kt2 * 32 + l31) * 64 + (((dt * 2 + hi) ^ swz) << 3)];
                    sacc = __builtin_amdgcn_mfma_f32_32x32x16_bf16(kf, qf[dt], sacc, 0, 0, 0);
                }
                __builtin_amdgcn_s_setprio(0);

                if (kb == wq0) {
#pragma unroll
                    for (int r = 0; r < 16; r++) {
                        int kr = (r & 3) + 8 * (r >> 2) + 4 * hi;
                        sacc[r] = (kr > l31) ? -1e30f : sacc[r];
                    }
                }

#pragma unroll
                for (int r = 0; r < 16; r++) sacc[r] = __builtin_amdgcn_exp2f(sacc[r]);
                lrow += sum16(sacc);

                bf16x8 pf[2];
                packp(sacc, pf);

                __builtin_amdgcn_s_setprio(1);
#pragma unroll
                for (int g = 0; g < 2; g++) {
                    bf16x8 vf0 = *(const bf16x8*)&Vs[l31 * 64 + (((kt2 * 4 + g * 2 + hi) ^ swz) << 3)];
                    oacc0 = __builtin_amdgcn_mfma_f32_32x32x16_bf16(vf0, pf[g], oacc0, 0, 0, 0);
                    bf16x8 vf1 = *(const bf16x8*)&Vs[(32 + l31) * 64 + (((kt2 * 4 + g * 2 + hi) ^ swz) << 3)];
                    oacc1 = __builtin_amdgcn_mfma_f32_32x32x16_bf16(vf1, pf[g], oacc1, 0, 0, 0);
                }
                __builtin_amdgcn_s_setprio(0);
            }
        }
    }

    float lsum = lrow + __shfl_xor(lrow, 32);
    float linv = 1.0f / lsum;
    unsigned short* op = O + (size_t)(b * SS + wq0 + l31) * 1024 + h * 64 + hi * 4;
#pragma unroll
    for (int g = 0; g < 4; g++) {
        uint2 u;
        u.x = cvtpk(oacc0[4 * g + 0] * linv, oacc0[4 * g + 1] * linv);
        u.y = cvtpk(oacc0[4 * g + 2] * linv, oacc0[4 * g + 3] * linv);
        *(uint2*)&op[g * 8] = u;
        uint2 v;
        v.x = cvtpk(oacc1[4 * g + 0] * linv, oacc1[4 * g + 1] * linv);
        v.y = cvtpk(oacc1[4 * g + 2] * linv, oacc1[4 * g + 3] * linv);
        *(uint2*)&op[32 + g * 8] = v;
    }
}

// ---------------- launch ----------------
extern "C" void kernel_launch(void* const* d_in, const int* in_sizes, int n_in,
                              void* d_out, int out_size, void* d_ws, size_t ws_size,
                              hipStream_t stream) {
    const float* x  = (const float*)d_in[0];
    const float* wq = (const float*)d_in[1];
    const float* wk = (const float*)d_in[2];
    const float* wv = (const float*)d_in[3];
    const float* wo = (const float*)d_in[4];
    float* out = (float*)d_out;

    unsigned short* xb    = (unsigned short*)d_ws;
    unsigned short* wqkvb = xb + (size_t)MM * DD;              // [3072][1024] (+wo contiguous after)
    unsigned short* wob   = wqkvb + (size_t)3 * DD * DD;
    unsigned short* QKV   = wob + (size_t)DD * DD;             // [8192][3072]
    unsigned short* Ob    = QKV + (size_t)MM * 3 * DD;         // [8192][1024]
    unsigned short* Vtb   = xb;                                // alias (xb dead after gemm8)

    k_prep<<<12288, 256, 0, stream>>>(x, wq, wk, wv, wo, xb, wqkvb);

    // fused QKV projection via BK=32 256^2 (2 blocks/CU): C[8192,3072] = x @ [wq;wk;wv]^T
    dim3 gq(3 * DD / 256, MM / 256);
    k_gemm8<<<gq, 512, 0, stream>>>(xb, wqkvb, QKV, 3 * DD);

    // fused rope(Q,K) + V-transpose
    k_ropevt<<<16384 + 2048, 256, 0, stream>>>(QKV, Vtb);

    dim3 ga(BB * HH, SS / 256);   // bh fastest -> same head on same XCD
    k_attn<<<ga, 512, 0, stream>>>(QKV, Vtb, Ob);

    // O-projection: m97 128^2 (best measured for this shape)
    dim3 gg(DD / 128, MM / 128);
    k_gemm<1><<<gg, 256, 0, stream>>>(Ob, wob, (void*)out, DD);
}

// Round 19
// 176.156 us; speedup vs baseline: 1.0717x; 1.0717x over previous
//
#include <hip/hip_runtime.h>

#define DEV __device__ __forceinline__

typedef float f32x4 __attribute__((ext_vector_type(4)));
typedef float f32x16 __attribute__((ext_vector_type(16)));
typedef __bf16 bf16x8 __attribute__((ext_vector_type(8)));
typedef unsigned u32x4 __attribute__((ext_vector_type(4)));
typedef unsigned short u16x8 __attribute__((ext_vector_type(8)));

static constexpr int BB = 4, SS = 2048, DD = 1024, HH = 16;
static constexpr int MM = BB * SS;          // 8192 rows
static constexpr float LOG2_THETA_OVER_HALF = 0.4152410118609203f; // log2(10000)/32
static constexpr float SCL2 = 0.18033688011112042f;                // 0.125 * log2(e)

DEV unsigned short f2b(float f) {
    unsigned u = __float_as_uint(f);
    unsigned r = (u + 0x7fffu + ((u >> 16) & 1u)) >> 16;
    return (unsigned short)r;
}
DEV float b2f(unsigned short h) { return __uint_as_float(((unsigned)h) << 16); }

DEV void gload16(const void* g, void* l) {
    __builtin_amdgcn_global_load_lds((const __attribute__((address_space(1))) void*)g,
                                     (__attribute__((address_space(3))) void*)l, 16, 0, 0);
}

DEV unsigned cvtpk(float lo, float hi) {
    unsigned r;
    asm("v_cvt_pk_bf16_f32 %0, %1, %2" : "=v"(r) : "v"(lo), "v"(hi));
    return r;
}

#define PH_BAR do { __builtin_amdgcn_sched_barrier(0); __builtin_amdgcn_s_barrier(); __builtin_amdgcn_sched_barrier(0); } while (0)

// ---------------- fused prep: fp32->bf16 for x (blocks 0..8191) and weights (8192..12287) ----------------
__global__ __launch_bounds__(256) void k_prep(const float* __restrict__ x,
                                              const float* __restrict__ wq, const float* __restrict__ wk,
                                              const float* __restrict__ wv, const float* __restrict__ wo,
                                              unsigned short* __restrict__ xb,
                                              unsigned short* __restrict__ wqkvb) {
    int bid = blockIdx.x;
    if (bid < 8192) {
        int i = (bid * 256 + threadIdx.x) * 4;
        float4 v = *reinterpret_cast<const float4*>(x + i);
        ushort4 o;
        o.x = f2b(v.x); o.y = f2b(v.y); o.z = f2b(v.z); o.w = f2b(v.w);
        *reinterpret_cast<ushort4*>(xb + i) = o;
    } else {
        int b2 = bid - 8192;
        int t = b2 >> 10;
        const float* src = (t == 0) ? wq : (t == 1) ? wk : (t == 2) ? wv : wo;
        int i = ((b2 & 1023) * 256 + threadIdx.x) * 4;
        float4 v = *reinterpret_cast<const float4*>(src + i);
        ushort4 o;
        o.x = f2b(v.x); o.y = f2b(v.y); o.z = f2b(v.z); o.w = f2b(v.w);
        *reinterpret_cast<ushort4*>(wqkvb + (size_t)t * DD * DD + i) = o;
    }
}

// ---------------- 8-phase 256x256 NT GEMM (K=1024), bf16 out — round-12 proven (BK=64) ----------------
__global__ __launch_bounds__(512, 2) void k_gemm8(const unsigned short* __restrict__ A,
                                                  const unsigned short* __restrict__ Bw,
                                                  unsigned short* __restrict__ C, int ldc) {
    __shared__ __align__(16) unsigned short LdsA[4][128 * 64];
    __shared__ __align__(16) unsigned short LdsB[4][128 * 64];
    const int tid = threadIdx.x, lane = tid & 63, wid = tid >> 6;
    const int wm = wid >> 2, wn = wid & 3;
    const int fr = lane & 15, l4 = lane >> 4, sw = fr & 7;
    const int m0 = blockIdx.y * 256, n0 = blockIdx.x * 256;

    const int r0 = tid >> 3;                  // 0..63
    const int cg = (tid & 7) ^ (r0 & 7);      // pre-swizzled source chunk
    const unsigned short* aS = A  + (size_t)(m0 + r0) * 1024 + (cg << 3);
    const unsigned short* bS = Bw + (size_t)(n0 + r0) * 1024 + (cg << 3);
    unsigned short* dA = &LdsA[0][0];
    unsigned short* dB = &LdsB[0][0];
    const int dOf = wid * 512;

    f32x4 acc[8][4] = {};

#define STG(src, base, slot) do {                         \
        unsigned short* d_ = (base) + (slot) * 8192 + dOf;\
        gload16((src), d_);                               \
        gload16((src) + 64 * 1024, d_ + 4096);            \
    } while (0)

#pragma unroll
    for (int T = 0; T < 2; ++T) {
        STG(bS + T * 64,          dB, (2 * T) & 3);
        STG(bS + T * 64 + 131072, dB, (2 * T + 1) & 3);
        STG(aS + T * 64,          dA, (2 * T) & 3);
        STG(aS + T * 64 + 131072, dA, (2 * T + 1) & 3);
    }

    bf16x8 aF[4][2], bL[2][2], bH[2][2];

    for (int T = 0; T < 16; ++T) {
        if (T < 15) { asm volatile("s_waitcnt vmcnt(8)" ::: "memory"); }
        else        { asm volatile("s_waitcnt vmcnt(0)" ::: "memory"); }
        PH_BAR;

        const unsigned short* As_ = &LdsA[(2 * T + wm) & 3][0];
        const unsigned short* Bs_ = &LdsB[(2 * T + (wn >> 1)) & 3][0];
        const int bro = (wn & 1) * 64;

        // ---- ph0: read A m0-3 + B n0-1; MFMA m0-3 x n0-1 ----
#pragma unroll
        for (int m = 0; m < 4; ++m)
#pragma unroll
            for (int kk = 0; kk < 2; ++kk)
                aF[m][kk] = *(const bf16x8*)&As_[(m * 16 + fr) * 64 + ((((kk << 2) | l4) ^ sw) << 3)];
#pragma unroll
        for (int n = 0; n < 2; ++n)
#pragma unroll
            for (int kk = 0; kk < 2; ++kk)
                bL[n][kk] = *(const bf16x8*)&Bs_[(bro + n * 16 + fr) * 64 + ((((kk << 2) | l4) ^ sw) << 3)];
        __builtin_amdgcn_s_setprio(1);
#pragma unroll
        for (int m = 0; m < 4; ++m)
#pragma unroll
            for (int n = 0; n < 2; ++n)
#pragma unroll
                for (int kk = 0; kk < 2; ++kk)
                    acc[m][n] = __builtin_amdgcn_mfma_f32_16x16x32_bf16(aF[m][kk], bL[n][kk], acc[m][n], 0, 0, 0);
        __builtin_amdgcn_s_setprio(0);
        PH_BAR;

        // ---- ph1: read B n2-3; MFMA m0-3 x n2-3 ----
#pragma unroll
        for (int n = 0; n < 2; ++n)
#pragma unroll
            for (int kk = 0; kk < 2; ++kk)
                bH[n][kk] = *(const bf16x8*)&Bs_[(bro + (n + 2) * 16 + fr) * 64 + ((((kk << 2) | l4) ^ sw) << 3)];
        __builtin_amdgcn_s_setprio(1);
#pragma unroll
        for (int m = 0; m < 4; ++m)
#pragma unroll
            for (int n = 0; n < 2; ++n)
#pragma unroll
                for (int kk = 0; kk < 2; ++kk)
                    acc[m][n + 2] = __builtin_amdgcn_mfma_f32_16x16x32_bf16(aF[m][kk], bH[n][kk], acc[m][n + 2], 0, 0, 0);
        __builtin_amdgcn_s_setprio(0);
        PH_BAR;

        // ---- ph2: read A m4-7; STG B(T+2); MFMA m4-7 x n2-3 ----
#pragma unroll
        for (int m = 0; m < 4; ++m)
#pragma unroll
            for (int kk = 0; kk < 2; ++kk)
                aF[m][kk] = *(const bf16x8*)&As_[((m + 4) * 16 + fr) * 64 + ((((kk << 2) | l4) ^ sw) << 3)];
        if (T + 2 < 16) {
            STG(bS + (T + 2) * 64,          dB, (2 * T) & 3);
            STG(bS + (T + 2) * 64 + 131072, dB, (2 * T + 1) & 3);
        }
        __builtin_amdgcn_s_setprio(1);
#pragma unroll
        for (int m = 0; m < 4; ++m)
#pragma unroll
            for (int n = 0; n < 2; ++n)
#pragma unroll
                for (int kk = 0; kk < 2; ++kk)
                    acc[m + 4][n + 2] = __builtin_amdgcn_mfma_f32_16x16x32_bf16(aF[m][kk], bH[n][kk], acc[m + 4][n + 2], 0, 0, 0);
        __builtin_amdgcn_s_setprio(0);
        PH_BAR;

        // ---- ph3: STG A(T+2); MFMA m4-7 x n0-1 ----
        if (T + 2 < 16) {
            STG(aS + (T + 2) * 64,          dA, (2 * T) & 3);
            STG(aS + (T + 2) * 64 + 131072, dA, (2 * T + 1) & 3);
        }
        __builtin_amdgcn_s_setprio(1);
#pragma unroll
        for (int m = 0; m < 4; ++m)
#pragma unroll
            for (int n = 0; n < 2; ++n)
#pragma unroll
                for (int kk = 0; kk < 2; ++kk)
                    acc[m + 4][n] = __builtin_amdgcn_mfma_f32_16x16x32_bf16(aF[m][kk], bL[n][kk], acc[m + 4][n], 0, 0, 0);
        __builtin_amdgcn_s_setprio(0);
        // ph3-end barrier provided by next boundary's PH_BAR
    }
#undef STG

    const int rb = l4 * 4;
#pragma unroll
    for (int m = 0; m < 8; ++m)
#pragma unroll
        for (int n = 0; n < 4; ++n)
#pragma unroll
            for (int r = 0; r < 4; ++r) {
                int row = m0 + wm * 128 + m * 16 + rb + r;
                int col = n0 + wn * 64 + n * 16 + fr;
                C[(size_t)row * ldc + col] = f2b(acc[m][n][r]);
            }
}

// ---------------- NT GEMM (m97 128x128): C[M,N] = A * Bw^T — proven O-proj ----------------
template <int OUTF32>
__global__ __launch_bounds__(256) void k_gemm(const unsigned short* __restrict__ A,
                                              const unsigned short* __restrict__ Bw,
                                              void* __restrict__ Cp, int ldc) {
    __shared__ __align__(16) unsigned short As[128 * 32];
    __shared__ __align__(16) unsigned short Bs[128 * 32];
    const int tid = threadIdx.x;
    const int lane = tid & 63, wid = tid >> 6;
    const int wm = wid >> 1, wn = wid & 1;
    const int fr = lane & 15, fk8 = (lane >> 4) * 8;
    const int m0 = blockIdx.y * 128, n0 = blockIdx.x * 128;
    const int r0 = tid >> 2, c0 = (tid & 3) * 8;

    f32x4 acc[4][4] = {};

    for (int kt = 0; kt < 1024; kt += 32) {
        gload16(&A[(size_t)(m0 + r0) * 1024 + kt + c0],       (unsigned short*)As + wid * 512);
        gload16(&A[(size_t)(m0 + 64 + r0) * 1024 + kt + c0],  (unsigned short*)As + 2048 + wid * 512);
        gload16(&Bw[(size_t)(n0 + r0) * 1024 + kt + c0],      (unsigned short*)Bs + wid * 512);
        gload16(&Bw[(size_t)(n0 + 64 + r0) * 1024 + kt + c0], (unsigned short*)Bs + 2048 + wid * 512);
        __syncthreads();

        bf16x8 af[4], bfv[4];
#pragma unroll
        for (int i = 0; i < 4; i++)
            af[i] = *(const bf16x8*)&As[(wm * 64 + i * 16 + fr) * 32 + fk8];
#pragma unroll
        for (int j = 0; j < 4; j++)
            bfv[j] = *(const bf16x8*)&Bs[(wn * 64 + j * 16 + fr) * 32 + fk8];
#pragma unroll
        for (int i = 0; i < 4; i++)
#pragma unroll
            for (int j = 0; j < 4; j++)
                acc[i][j] = __builtin_amdgcn_mfma_f32_16x16x32_bf16(af[i], bfv[j], acc[i][j], 0, 0, 0);
        __syncthreads();
    }

    const int rb = (lane >> 4) * 4;
#pragma unroll
    for (int i = 0; i < 4; i++)
#pragma unroll
        for (int j = 0; j < 4; j++)
#pragma unroll
            for (int r = 0; r < 4; r++) {
                int row = m0 + wm * 64 + i * 16 + rb + r;
                int col = n0 + wn * 64 + j * 16 + fr;
                if (OUTF32) ((float*)Cp)[(size_t)row * ldc + col] = acc[i][j][r];
                else        ((unsigned short*)Cp)[(size_t)row * ldc + col] = f2b(acc[i][j][r]);
            }
}

// ---------------- fused RoPE(Q,K) + V-transpose, co-dispatched ----------------
__global__ __launch_bounds__(256) void k_ropevt(unsigned short* __restrict__ QKV,
                                                unsigned short* __restrict__ Vt) {
    __shared__ unsigned short T[64 * 65];
    const int bid = blockIdx.x, tid = threadIdx.x;
    if (bid < 16384) {
        int g = bid * 256 + tid;              // pair index over M*512
        int m = g >> 9, p = g & 511;
        int i = p & 31;
        int s = m & (SS - 1);
        int col = ((p >> 5) << 6) + (i << 1); // h*64 + 2i
        float inv = exp2f(-(float)i * LOG2_THETA_OVER_HALF);
        float ang = (float)s * inv;
        float sn, cs;
        sincosf(ang, &sn, &cs);
        unsigned short* q2 = QKV + (size_t)m * 3072 + col;
        unsigned short* k2 = q2 + 1024;
        float q1 = b2f(q2[0]), q2v = b2f(q2[1]);
        float k1 = b2f(k2[0]), k2v = b2f(k2[1]);
        q2[0] = f2b((q1 * cs - q2v * sn) * SCL2);
        q2[1] = f2b((q1 * sn + q2v * cs) * SCL2);
        k2[0] = f2b(k1 * cs - k2v * sn);
        k2[1] = f2b(k1 * sn + k2v * cs);
    } else {
        const int v2 = bid - 16384;
        const int s0 = (v2 & 31) * 64, bh = v2 >> 5;
        const int b = bh >> 4, h = bh & 15;
        const int r = tid >> 3, c8 = (tid & 7) * 8;
        const unsigned short* V = QKV + 2 * DD;
#pragma unroll
        for (int p = 0; p < 2; p++) {
            int row = p * 32 + r;
            u16x8 v = *(const u16x8*)&V[(size_t)(b * SS + s0 + row) * 3072 + h * 64 + c8];
#pragma unroll
            for (int j = 0; j < 8; j++) T[(c8 + j) * 65 + row] = v[j];
        }
        __syncthreads();
#pragma unroll
        for (int p = 0; p < 2; p++) {
            int d = p * 32 + r;
            u16x8 o;
#pragma unroll
            for (int j = 0; j < 8; j++) o[j] = T[d * 65 + c8 + j];
            *(u16x8*)&Vt[((size_t)bh * 64 + d) * 2048 + s0 + c8] = o;
        }
    }
}

// pack exp'd scores into PV B-operand via permlane32_swap
DEV void packp(const f32x16& s, bf16x8* pf) {
#pragma unroll
    for (int g = 0; g < 2; g++) {
        unsigned w0 = cvtpk(s[8 * g + 0], s[8 * g + 1]);
        unsigned w1 = cvtpk(s[8 * g + 2], s[8 * g + 3]);
        unsigned w2 = cvtpk(s[8 * g + 4], s[8 * g + 5]);
        unsigned w3 = cvtpk(s[8 * g + 6], s[8 * g + 7]);
        asm("v_permlane32_swap_b32 %0, %1" : "+v"(w0), "+v"(w2));
        asm("v_permlane32_swap_b32 %0, %1" : "+v"(w1), "+v"(w3));
        u32x4 pd;
        pd[0] = w0; pd[1] = w1; pd[2] = w2; pd[3] = w3;
        pf[g] = __builtin_bit_cast(bf16x8, pd);
    }
}

DEV float sum16(const f32x16& s) {
    return (((s[0] + s[1]) + (s[2] + s[3])) + ((s[4] + s[5]) + (s[6] + s[7]))) +
           (((s[8] + s[9]) + (s[10] + s[11])) + (((s[12] + s[13]) + (s[14] + s[15]))));
}

// ---------------- causal flash attention: 8 waves x 32 q-rows, swapped 32x32 MFMA ----------------
// RING-3 K/V buffers + counted vmcnt (round-17, neutral-kept).
__global__ __launch_bounds__(512, 4) void k_attn(const unsigned short* __restrict__ QKV,
                                                 const unsigned short* __restrict__ Vt,
                                                 unsigned short* __restrict__ O) {
    __shared__ __align__(16) unsigned short Kbuf[3][64 * 64];
    __shared__ __align__(16) unsigned short Vbuf[3][64 * 64];
    const int tid = threadIdx.x, lane = tid & 63, wid = tid >> 6;
    const int l31 = lane & 31, hi = lane >> 5;
    const int bh = blockIdx.x, b = bh >> 4, h = bh & 15;
    const int qt = gridDim.y - 1 - blockIdx.y;       // long blocks first
    const int q0 = qt * 256;
    const int wq0 = q0 + wid * 32;
    const int tdw = wq0 >> 6;
    const int nk = (q0 + 256) >> 6;                  // >= 4 always

    const int srow = tid >> 3, sc = tid & 7;
    const unsigned short* ksrc = QKV + 1024 + ((size_t)(b * SS) + srow) * 3072 + h * 64 + ((sc ^ (srow & 7)) << 3);
    const unsigned short* vsrc = Vt + ((size_t)(bh * 64) + srow) * 2048 + ((sc ^ (srow & 7)) << 3);

    const unsigned short* qp = QKV + (size_t)(b * SS + wq0 + l31) * 3072 + h * 64;
    bf16x8 qf[4];
#pragma unroll
    for (int dt = 0; dt < 4; dt++) qf[dt] = *(const bf16x8*)(qp + dt * 16 + hi * 8);

    f32x16 oacc0 = {}, oacc1 = {};
    float lrow = 0.f;
    const int swz = l31 & 7;

    // prologue: stage tiles 0 and 1
    gload16(ksrc,             (unsigned short*)Kbuf[0] + wid * 512);
    gload16(vsrc,             (unsigned short*)Vbuf[0] + wid * 512);
    gload16(ksrc + 64 * 3072, (unsigned short*)Kbuf[1] + wid * 512);
    gload16(vsrc + 64,        (unsigned short*)Vbuf[1] + wid * 512);

    for (int t = 0; t < nk; t++) {
        if (t + 1 < nk) { asm volatile("s_waitcnt vmcnt(2) lgkmcnt(0)" ::: "memory"); }
        else            { asm volatile("s_waitcnt vmcnt(0) lgkmcnt(0)" ::: "memory"); }
        PH_BAR;
        if (t + 2 < nk) {
            int nb = (t + 2) % 3;
            gload16(ksrc + (size_t)(t + 2) * 64 * 3072, (unsigned short*)Kbuf[nb] + wid * 512);
            gload16(vsrc + (t + 2) * 64,                (unsigned short*)Vbuf[nb] + wid * 512);
        }
        if (t > tdw) continue;
        const unsigned short* Ks = Kbuf[t % 3];
        const unsigned short* Vs = Vbuf[t % 3];

        if (t < tdw) {
            // ---- full 64-k tile: two independent 32-k chains, straight-line (ILP) ----
            f32x16 s0 = {}, s1 = {};
            __builtin_amdgcn_s_setprio(1);
#pragma unroll
            for (int dt = 0; dt < 4; dt++) {
                bf16x8 kf = *(const bf16x8*)&Ks[l31 * 64 + (((dt * 2 + hi) ^ swz) << 3)];
                s0 = __builtin_amdgcn_mfma_f32_32x32x16_bf16(kf, qf[dt], s0, 0, 0, 0);
            }
#pragma unroll
            for (int dt = 0; dt < 4; dt++) {
                bf16x8 kf = *(const bf16x8*)&Ks[(32 + l31) * 64 + (((dt * 2 + hi) ^ swz) << 3)];
                s1 = __builtin_amdgcn_mfma_f32_32x32x16_bf16(kf, qf[dt], s1, 0, 0, 0);
            }
            __builtin_amdgcn_s_setprio(0);
#pragma unroll
            for (int r = 0; r < 16; r++) {
                s0[r] = __builtin_amdgcn_exp2f(s0[r]);
                s1[r] = __builtin_amdgcn_exp2f(s1[r]);
            }
            lrow += sum16(s0) + sum16(s1);
            bf16x8 pA[2], pB[2];
            packp(s0, pA);
            packp(s1, pB);
            __builtin_amdgcn_s_setprio(1);
#pragma unroll
            for (int g = 0; g < 2; g++) {
                bf16x8 vf0 = *(const bf16x8*)&Vs[l31 * 64 + (((g * 2 + hi) ^ swz) << 3)];
                oacc0 = __builtin_amdgcn_mfma_f32_32x32x16_bf16(vf0, pA[g], oacc0, 0, 0, 0);
                bf16x8 vf1 = *(const bf16x8*)&Vs[(32 + l31) * 64 + (((g * 2 + hi) ^ swz) << 3)];
                oacc1 = __builtin_amdgcn_mfma_f32_32x32x16_bf16(vf1, pA[g], oacc1, 0, 0, 0);
            }
#pragma unroll
            for (int g = 0; g < 2; g++) {
                bf16x8 vf0 = *(const bf16x8*)&Vs[l31 * 64 + (((4 + g * 2 + hi) ^ swz) << 3)];
                oacc0 = __builtin_amdgcn_mfma_f32_32x32x16_bf16(vf0, pB[g], oacc0, 0, 0, 0);
                bf16x8 vf1 = *(const bf16x8*)&Vs[(32 + l31) * 64 + (((4 + g * 2 + hi) ^ swz) << 3)];
                oacc1 = __builtin_amdgcn_mfma_f32_32x32x16_bf16(vf1, pB[g], oacc1, 0, 0, 0);
            }
            __builtin_amdgcn_s_setprio(0);
        } else {
            // ---- diagonal tile: masked path ----
#pragma unroll
            for (int kt2 = 0; kt2 < 2; kt2++) {
                const int kb = t * 64 + kt2 * 32;
                if (kb > wq0) break;

                f32x16 sacc = {};
                __builtin_amdgcn_s_setprio(1);
#pragma unroll
                for (int dt = 0; dt < 4; dt++) {
                    bf16x8 kf = *(const bf16x8*)&Ks[(kt2 * 32 + l31) * 64 + (((dt * 2 + hi) ^ swz) << 3)];
                    sacc = __builtin_amdgcn_mfma_f32_32x32x16_bf16(kf, qf[dt], sacc, 0, 0, 0);
                }
                __builtin_amdgcn_s_setprio(0);

                if (kb == wq0) {
#pragma unroll
                    for (int r = 0; r < 16; r++) {
                        int kr = (r & 3) + 8 * (r >> 2) + 4 * hi;
                        sacc[r] = (kr > l31) ? -1e30f : sacc[r];
                    }
                }

#pragma unroll
                for (int r = 0; r < 16; r++) sacc[r] = __builtin_amdgcn_exp2f(sacc[r]);
                lrow += sum16(sacc);

                bf16x8 pf[2];
                packp(sacc, pf);

                __builtin_amdgcn_s_setprio(1);
#pragma unroll
                for (int g = 0; g < 2; g++) {
                    bf16x8 vf0 = *(const bf16x8*)&Vs[l31 * 64 + (((kt2 * 4 + g * 2 + hi) ^ swz) << 3)];
                    oacc0 = __builtin_amdgcn_mfma_f32_32x32x16_bf16(vf0, pf[g], oacc0, 0, 0, 0);
                    bf16x8 vf1 = *(const bf16x8*)&Vs[(32 + l31) * 64 + (((kt2 * 4 + g * 2 + hi) ^ swz) << 3)];
                    oacc1 = __builtin_amdgcn_mfma_f32_32x32x16_bf16(vf1, pf[g], oacc1, 0, 0, 0);
                }
                __builtin_amdgcn_s_setprio(0);
            }
        }
    }

    float lsum = lrow + __shfl_xor(lrow, 32);
    float linv = 1.0f / lsum;
    unsigned short* op = O + (size_t)(b * SS + wq0 + l31) * 1024 + h * 64 + hi * 4;
#pragma unroll
    for (int g = 0; g < 4; g++) {
        uint2 u;
        u.x = cvtpk(oacc0[4 * g + 0] * linv, oacc0[4 * g + 1] * linv);
        u.y = cvtpk(oacc0[4 * g + 2] * linv, oacc0[4 * g + 3] * linv);
        *(uint2*)&op[g * 8] = u;
        uint2 v;
        v.x = cvtpk(oacc1[4 * g + 0] * linv, oacc1[4 * g + 1] * linv);
        v.y = cvtpk(oacc1[4 * g + 2] * linv, oacc1[4 * g + 3] * linv);
        *(uint2*)&op[32 + g * 8] = v;
    }
}

// ---------------- launch ----------------
extern "C" void kernel_launch(void* const* d_in, const int* in_sizes, int n_in,
                              void* d_out, int out_size, void* d_ws, size_t ws_size,
                              hipStream_t stream) {
    const float* x  = (const float*)d_in[0];
    const float* wq = (const float*)d_in[1];
    const float* wk = (const float*)d_in[2];
    const float* wv = (const float*)d_in[3];
    const float* wo = (const float*)d_in[4];
    float* out = (float*)d_out;

    unsigned short* xb    = (unsigned short*)d_ws;
    unsigned short* wqkvb = xb + (size_t)MM * DD;              // [3072][1024] (+wo contiguous after)
    unsigned short* wob   = wqkvb + (size_t)3 * DD * DD;
    unsigned short* QKV   = wob + (size_t)DD * DD;             // [8192][3072]
    unsigned short* Ob    = QKV + (size_t)MM * 3 * DD;         // [8192][1024]
    unsigned short* Vtb   = xb;                                // alias (xb dead after gemm8)

    k_prep<<<12288, 256, 0, stream>>>(x, wq, wk, wv, wo, xb, wqkvb);

    // fused QKV projection via 8-phase 256^2 (round-12 best): C[8192,3072] = x @ [wq;wk;wv]^T
    dim3 gq(3 * DD / 256, MM / 256);
    k_gemm8<<<gq, 512, 0, stream>>>(xb, wqkvb, QKV, 3 * DD);

    // fused rope(Q,K) + V-transpose
    k_ropevt<<<16384 + 2048, 256, 0, stream>>>(QKV, Vtb);

    dim3 ga(BB * HH, SS / 256);   // bh fastest -> same head on same XCD
    k_attn<<<ga, 512, 0, stream>>>(QKV, Vtb, Ob);

    // O-projection: m97 128^2 (best measured for this shape)
    dim3 gg(DD / 128, MM / 128);
    k_gemm<1><<<gg, 256, 0, stream>>>(Ob, wob, (void*)out, DD);
}